// Round 12
// baseline (110.179 us; speedup 1.0000x reference)
//
#include <hip/hip_runtime.h>
#include <hip/hip_bf16.h>

typedef __attribute__((ext_vector_type(8))) short short8;
typedef __attribute__((ext_vector_type(8))) unsigned short u16x8;
typedef __attribute__((ext_vector_type(4))) unsigned short u16x4;
typedef __attribute__((ext_vector_type(4))) float f32x4;
typedef __attribute__((ext_vector_type(4))) unsigned int u32x4;

#define L2E 1.44269504f

__device__ __forceinline__ unsigned short f2bf(float f){
  unsigned u = __float_as_uint(f);
  u += 0x7fffu + ((u >> 16) & 1u);
  return (unsigned short)(u >> 16);
}
// pack two f32 -> u32 of 2 bf16, RNE, lo in bits[15:0]
__device__ __forceinline__ unsigned pk_bf16(float lo, float hi){
  unsigned a = __float_as_uint(lo);
  a += 0x7fffu + ((a >> 16) & 1u);
  unsigned b = __float_as_uint(hi);
  b += 0x7fffu + ((b >> 16) & 1u);
  return (a >> 16) | (b & 0xffff0000u);
}
// async global->LDS, 16B per lane: LDS dest = uniform base + lane*16,
// global src = per-lane address. Counts on vmcnt.
__device__ __forceinline__ void gl_lds16(const void* g, void* l){
  __builtin_amdgcn_global_load_lds(
      (const __attribute__((address_space(1))) unsigned*)g,
      (__attribute__((address_space(3))) unsigned*)l, 16, 0, 0);
}

// ---------------- prep: fold score_w through q_w / kv_w ----------------
__global__ void prep_vecs(const float* __restrict__ qw, const float* __restrict__ qb,
                          const float* __restrict__ kvw, const float* __restrict__ kvb,
                          const float* __restrict__ scw, const float* __restrict__ scb,
                          float* __restrict__ qv, float* __restrict__ kvv,
                          float* __restrict__ cqck){
  int d = threadIdx.x; // 0..127
  const float4* qr = (const float4*)(qw + d*128);
  const float4* kr = (const float4*)(kvw + d*256);
  float a = 0.f, c = 0.f;
  #pragma unroll 8
  for (int i = 0; i < 32; ++i){
    float4 q4 = qr[i];
    float4 w4 = *(const float4*)(scw + i*4);
    a = fmaf(q4.x, w4.x, a); a = fmaf(q4.y, w4.y, a);
    a = fmaf(q4.z, w4.z, a); a = fmaf(q4.w, w4.w, a);
    float4 k4 = kr[i];
    float4 v4 = *(const float4*)(scw + 128 + i*4);
    c = fmaf(k4.x, v4.x, c); c = fmaf(k4.y, v4.y, c);
    c = fmaf(k4.z, v4.z, c); c = fmaf(k4.w, v4.w, c);
  }
  qv[d] = a; kvv[d] = c;
  if (d == 0){
    float cq = scb[0], ck = 0.f;
    #pragma unroll 8
    for (int i = 0; i < 32; ++i){
      float4 qb4 = *(const float4*)(qb + i*4);
      float4 w4  = *(const float4*)(scw + i*4);
      float4 kb4 = *(const float4*)(kvb + i*4);
      float4 v4  = *(const float4*)(scw + 128 + i*4);
      cq = fmaf(qb4.x, w4.x, cq); cq = fmaf(qb4.y, w4.y, cq);
      cq = fmaf(qb4.z, w4.z, cq); cq = fmaf(qb4.w, w4.w, cq);
      ck = fmaf(kb4.x, v4.x, ck); ck = fmaf(kb4.y, v4.y, ck);
      ck = fmaf(kb4.z, v4.z, ck); ck = fmaf(kb4.w, v4.w, ck);
    }
    cqck[0] = cq; cqck[1] = ck;
  }
}

// W2T[ho][din] = sum_h kv_w[din][128+h] * out_w[h][ho]   (bf16, transposed)
__global__ __launch_bounds__(256) void prep_w2(const float* __restrict__ kvw,
                          const float* __restrict__ kvb,
                          const float* __restrict__ outw, const float* __restrict__ outb,
                          unsigned short* __restrict__ w2t, float* __restrict__ c2){
  int blk = blockIdx.x;
  if (blk < 64){
    int idx = blk*256 + threadIdx.x;
    int di = idx >> 7, ho = idx & 127;
    const float* kr = kvw + di*256 + 128;
    float s = 0.f;
    for (int h = 0; h < 128; ++h) s = fmaf(kr[h], outw[h*128 + ho], s);
    w2t[ho*128 + di] = f2bf(s);
  } else if (threadIdx.x < 128){
    int ho = threadIdx.x;
    float s = outb[ho];
    for (int h = 0; h < 128; ++h) s = fmaf(kvb[128 + h], outw[h*128 + ho], s);
    c2[ho] = s;
  }
}

// sq'[b*1024+m] = L2E * (mf[b,m,:].qv + cq)
__global__ __launch_bounds__(256) void prep_sq(const float* __restrict__ mf,
                          const float* __restrict__ qv, const float* __restrict__ cqck,
                          float* __restrict__ sqp){
  int row = blockIdx.x*4 + (threadIdx.x >> 6);
  int lane = threadIdx.x & 63;
  float s = mf[row*128 + lane] * qv[lane] + mf[row*128 + 64 + lane] * qv[64 + lane];
  #pragma unroll
  for (int o = 32; o; o >>= 1) s += __shfl_xor(s, o, 64);
  if (lane == 0) sqp[row] = L2E * (s + cqck[0]);
}

// sk'[b*4096+c] = L2E*(of[b,c,:].kvv + ck)
// ofTk[b][ksg(128)][l4(4)][d(128)][8] = bf16(of[b][c][d]), c = ksg*32+l4*8+j
__global__ __launch_bounds__(256) void prep_sk_tr(const float* __restrict__ of,
                          const float* __restrict__ kvv, const float* __restrict__ cqck,
                          float* __restrict__ skp, unsigned short* __restrict__ ofTk){
  __shared__ unsigned short tile[64*130];
  int b  = blockIdx.x >> 6;
  int c0 = (blockIdx.x & 63) << 6;
  int t  = threadIdx.x;
  int r  = t >> 2, dq = (t & 3) << 5;
  const float* src = of + ((size_t)(b*4096 + c0 + r))*128 + dq;
  float part = 0.f;
  #pragma unroll
  for (int j = 0; j < 32; j += 4){
    float4 v = *(const float4*)(src + j);
    part = fmaf(v.x, kvv[dq + j],     part);
    part = fmaf(v.y, kvv[dq + j + 1], part);
    part = fmaf(v.z, kvv[dq + j + 2], part);
    part = fmaf(v.w, kvv[dq + j + 3], part);
    tile[r*130 + dq + j]     = f2bf(v.x);
    tile[r*130 + dq + j + 1] = f2bf(v.y);
    tile[r*130 + dq + j + 2] = f2bf(v.z);
    tile[r*130 + dq + j + 3] = f2bf(v.w);
  }
  part += __shfl_xor(part, 1, 64);
  part += __shfl_xor(part, 2, 64);
  if ((t & 3) == 0) skp[b*4096 + c0 + r] = L2E * (part + cqck[1]);
  __syncthreads();
  int d = t >> 1, chh = (t & 1) << 5;
  #pragma unroll
  for (int j = 0; j < 4; ++j){
    int cg = c0 + chh + j*8;
    int ksg = cg >> 5, l4g = (cg >> 3) & 3;
    u16x8 v;
    #pragma unroll
    for (int k = 0; k < 8; ++k) v[k] = tile[(chh + j*8 + k)*130 + d];
    *(u16x8*)(ofTk + (((size_t)(b*128 + ksg)*4 + l4g)*128 + d)*8) = v;
  }
}

// ---------------- main kernel: LDS mask ring + counted vmcnt ----------------
// Wave-private unit = (bmt=b*64+mt16, cs): 16 m-rows x 128 d, c-slice of
// 4096>>CSL2 in K-steps of 32 c. Mask streamed HBM->LDS ring (depth 4) via
// global_load_lds (zero VGPR in flight); sk slice preloaded to LDS once.
// B (ofTk, L2/L3-resident) JIT register loads. One counted vmcnt per kstep
// (steady 30, never 0) pins M(ks) completion; ring slot reuse guarded by
// lgkmcnt(0) before the overwriting DMA issue. Rowsum via ones-MFMA.

#define WVAL(KS) ((KS)==0 ? 0 : (KS)==1 ? 10 : (KS)==2 ? 20 : \
                  ((KS) >= NK-3 ? (24 + 2*(NK-1-(KS))) : 30))

#define KSTEP(KS) if ((KS) < NK) {                                               \
  asm volatile("s_waitcnt vmcnt(%0)" :: "i"(WVAL(KS)) : "memory");               \
  __builtin_amdgcn_sched_barrier(0);                                             \
  const unsigned short* bp = bbase + (size_t)(KS)*4096;                          \
  short8 b0 = *(const short8*)(bp);       short8 b1 = *(const short8*)(bp+128);  \
  short8 b2 = *(const short8*)(bp+256);   short8 b3 = *(const short8*)(bp+384);  \
  short8 b4 = *(const short8*)(bp+512);   short8 b5 = *(const short8*)(bp+640);  \
  short8 b6 = *(const short8*)(bp+768);   short8 b7 = *(const short8*)(bp+896);  \
  const char* ms = Mring + ((KS)&3)*2048;                                        \
  f32x4 m0v = *(const f32x4*)(ms + lB);                                          \
  f32x4 m1v = *(const f32x4*)(ms + 1024 + lB);                                   \
  f32x4 s0v = *(const f32x4*)(Sl + (KS)*128 + l4*32);                            \
  f32x4 s1v = *(const f32x4*)(Sl + (KS)*128 + l4*32 + 16);                       \
  asm volatile("s_waitcnt lgkmcnt(0)" ::: "memory");                             \
  __builtin_amdgcn_sched_barrier(0);                                             \
  if ((KS)+4 < NK){                                                              \
    gl_lds16(mrow + ((KS)+4)*32,     Mring + (((KS)+4)&3)*2048);                 \
    gl_lds16(mrow + ((KS)+4)*32 + 4, Mring + (((KS)+4)&3)*2048 + 1024);          \
  }                                                                              \
  float sx[8] = {s0v[0],s0v[1],s0v[2],s0v[3],s1v[0],s1v[1],s1v[2],s1v[3]};       \
  float mx[8] = {m0v[0],m0v[1],m0v[2],m0v[3],m1v[0],m1v[1],m1v[2],m1v[3]};       \
  float pv[8];                                                                   \
  _Pragma("unroll")                                                              \
  for (int j = 0; j < 8; ++j){                                                   \
    float s = sqv + sx[j];            /* log2-domain (pre-scaled by L2E) */      \
    s = fmaxf(s, 0.01f*s);            /* leaky (positively homogeneous) */       \
    s *= mx[j];                       /* mask: 0 -> exp2(0)=1 */                 \
    pv[j] = __builtin_amdgcn_exp2f(s);                                           \
  }                                                                              \
  u32x4 pkv;                                                                     \
  pkv[0] = pk_bf16(pv[0], pv[1]);  pkv[1] = pk_bf16(pv[2], pv[3]);               \
  pkv[2] = pk_bf16(pv[4], pv[5]);  pkv[3] = pk_bf16(pv[6], pv[7]);               \
  short8 pa = __builtin_bit_cast(short8, pkv);                                   \
  accS = __builtin_amdgcn_mfma_f32_16x16x32_bf16(pa, ones, accS, 0, 0, 0);       \
  acc0 = __builtin_amdgcn_mfma_f32_16x16x32_bf16(pa, b0, acc0, 0, 0, 0);         \
  acc1 = __builtin_amdgcn_mfma_f32_16x16x32_bf16(pa, b1, acc1, 0, 0, 0);         \
  acc2 = __builtin_amdgcn_mfma_f32_16x16x32_bf16(pa, b2, acc2, 0, 0, 0);         \
  acc3 = __builtin_amdgcn_mfma_f32_16x16x32_bf16(pa, b3, acc3, 0, 0, 0);         \
  acc4 = __builtin_amdgcn_mfma_f32_16x16x32_bf16(pa, b4, acc4, 0, 0, 0);         \
  acc5 = __builtin_amdgcn_mfma_f32_16x16x32_bf16(pa, b5, acc5, 0, 0, 0);         \
  acc6 = __builtin_amdgcn_mfma_f32_16x16x32_bf16(pa, b6, acc6, 0, 0, 0);         \
  acc7 = __builtin_amdgcn_mfma_f32_16x16x32_bf16(pa, b7, acc7, 0, 0, 0);         \
}

template<int CSL2>
__global__ __launch_bounds__(256, 4) void attn_main(
    const float* __restrict__ mask, const float* __restrict__ sqp,
    const float* __restrict__ skp, const unsigned short* __restrict__ ofTk,
    float* __restrict__ pacc, float* __restrict__ prs)
{
  constexpr int CS = 1 << CSL2;
  constexpr int NK = 128 >> CSL2;               // K-steps of 32 c
  constexpr int SBYTES = (4096 >> CSL2) * 4;    // sk slice bytes
  constexpr int SINSTS = SBYTES / 1024;
  __shared__ char lds[4][4*2048 + SBYTES];      // per-wave: 8KB M ring + S

  const int t = threadIdx.x, w = t >> 6, l = t & 63;
  const int l15 = l & 15, l4 = l >> 4;
  const int lB = l * 16;
  const int unit = blockIdx.x*4 + w;
  const int cs   = unit & (CS - 1);
  const int bmt  = unit >> CSL2;                // b*64 + mt16
  const int b    = bmt >> 6;
  const int m0   = (bmt & 63) << 4;
  const int c0   = cs << (12 - CSL2);

  char* Mring = &lds[w][0];
  char* Sl    = &lds[w][8192];

  const int grow = b*1024 + m0 + l15;
  const float sqv = sqp[grow];
  const float* mrow = mask + (size_t)grow*4096 + c0 + l4*8;   // per-lane src
  const float* srow = skp + b*4096 + c0;
  const unsigned short* bbase =
      ofTk + (((size_t)(b*128 + (c0 >> 5))*4 + l4)*128 + l15)*8;

  const short one_bf = (short)0x3F80;
  const short8 ones = {one_bf,one_bf,one_bf,one_bf,one_bf,one_bf,one_bf,one_bf};

  f32x4 acc0={0,0,0,0},acc1={0,0,0,0},acc2={0,0,0,0},acc3={0,0,0,0},
        acc4={0,0,0,0},acc5={0,0,0,0},acc6={0,0,0,0},acc7={0,0,0,0},
        accS={0,0,0,0};

  // prologue: S slice, then M ring slots 0..3 (issue order fixed by fences
  // only at kstep granularity; W values are permutation-safe within groups)
  #pragma unroll
  for (int i = 0; i < SINSTS; ++i)
    gl_lds16(srow + l*4 + i*256, Sl + i*1024);
  #pragma unroll
  for (int p = 0; p < 4; ++p){
    gl_lds16(mrow + p*32,     Mring + p*2048);
    gl_lds16(mrow + p*32 + 4, Mring + p*2048 + 1024);
  }

  KSTEP(0)  KSTEP(1)  KSTEP(2)  KSTEP(3)  KSTEP(4)  KSTEP(5)  KSTEP(6)  KSTEP(7)
  KSTEP(8)  KSTEP(9)  KSTEP(10) KSTEP(11) KSTEP(12) KSTEP(13) KSTEP(14) KSTEP(15)
  KSTEP(16) KSTEP(17) KSTEP(18) KSTEP(19) KSTEP(20) KSTEP(21) KSTEP(22) KSTEP(23)
  KSTEP(24) KSTEP(25) KSTEP(26) KSTEP(27) KSTEP(28) KSTEP(29) KSTEP(30) KSTEP(31)

  // rowsum from ones-MFMA: lane (l15==0, l4) holds rows l4*4+j
  if (l15 == 0) *(f32x4*)(prs + unit*16 + l4*4) = accS;

  // acc -> pacc[unit][col][row] (col = nt*16+l15, rows l4*4..+3)
  float* po = pacc + (size_t)unit*2048 + l15*16 + l4*4;
  *(f32x4*)(po + 0*256) = acc0;  *(f32x4*)(po + 1*256) = acc1;
  *(f32x4*)(po + 2*256) = acc2;  *(f32x4*)(po + 3*256) = acc3;
  *(f32x4*)(po + 4*256) = acc4;  *(f32x4*)(po + 5*256) = acc5;
  *(f32x4*)(po + 6*256) = acc6;  *(f32x4*)(po + 7*256) = acc7;
}

// ---------------- reduce partials + normalize + GEMM2 ----------------
__global__ __launch_bounds__(256) void reduce_gemm2(
    const float* __restrict__ pacc, const float* __restrict__ prs,
    const unsigned short* __restrict__ w2t, const float* __restrict__ c2,
    float* __restrict__ out, int csl2)
{
  __shared__ unsigned short A2[64*128];   // 16 KB, row stride 256 B, swizzled
  __shared__ float rs[64];                // inverse rowsums
  const int bmt64 = blockIdx.x;
  const int b = bmt64 >> 4, mt = bmt64 & 15;
  const int CS = 1 << csl2;
  const int t = threadIdx.x;

  f32x4 a[8];
  #pragma unroll
  for (int i = 0; i < 8; ++i) a[i] = {0.f,0.f,0.f,0.f};
  for (int cs = 0; cs < CS; ++cs){
    #pragma unroll
    for (int i = 0; i < 8; ++i){
      const int flat = (i*256 + t)*4;
      const int q = flat >> 11, f2 = flat & 2047;
      const float* pb = pacc + ((size_t)((bmt64*4 + q)*CS + cs))*2048 + f2;
      f32x4 v = *(const f32x4*)pb;
      a[i][0]+=v[0]; a[i][1]+=v[1]; a[i][2]+=v[2]; a[i][3]+=v[3];
    }
  }
  if (t < 64){
    float s = 0.f;
    const int q = t >> 4, r16 = t & 15;
    for (int cs = 0; cs < CS; ++cs) s += prs[((bmt64*4 + q)*CS + cs)*16 + r16];
    rs[t] = 1.f / s;
  }
  __syncthreads();
  #pragma unroll
  for (int i = 0; i < 8; ++i){
    const int flat = (i*256 + t)*4;
    const int q = flat >> 11, f2 = flat & 2047;
    const int col = f2 >> 4, r16 = f2 & 15;
    #pragma unroll
    for (int k = 0; k < 4; ++k){
      const int row = q*16 + r16 + k;
      unsigned short h = f2bf(a[i][k] * rs[row]);
      *(unsigned short*)((char*)A2 + row*256 + ((col*2) ^ ((row & 7) << 4))) = h;
    }
  }
  __syncthreads();

  const int w = t >> 6, l = t & 63, l15 = l & 15, l4 = l >> 4;
  f32x4 o[4][2];
  #pragma unroll
  for (int mf = 0; mf < 4; ++mf){ o[mf][0] = {0.f,0.f,0.f,0.f}; o[mf][1] = {0.f,0.f,0.f,0.f}; }
  const unsigned short* wp0 = w2t + (size_t)(w*32 + l15)*128 + l4*8;
  const char* ab = (const char*)A2 + l15*256;
  const int xa = (l15 & 7) << 4;
  #pragma unroll
  for (int ks = 0; ks < 4; ++ks){
    short8 b0 = *(const short8*)(wp0 + ks*32);
    short8 b1 = *(const short8*)(wp0 + 16*128 + ks*32);
    #pragma unroll
    for (int mf = 0; mf < 4; ++mf){
      short8 af = *(const short8*)(ab + mf*4096 + ((ks*64 + l4*16) ^ xa));
      o[mf][0] = __builtin_amdgcn_mfma_f32_16x16x32_bf16(af, b0, o[mf][0], 0, 0, 0);
      o[mf][1] = __builtin_amdgcn_mfma_f32_16x16x32_bf16(af, b1, o[mf][1], 0, 0, 0);
    }
  }
  #pragma unroll
  for (int mf = 0; mf < 4; ++mf)
    #pragma unroll
    for (int n = 0; n < 2; ++n){
      const int col = w*32 + n*16 + l15;
      const float cc = c2[col];
      #pragma unroll
      for (int j = 0; j < 4; ++j){
        const int row = mf*16 + l4*4 + j;
        out[((size_t)(b*1024 + mt*64 + row))*128 + col] = o[mf][n][j] + cc;
      }
    }
}

extern "C" void kernel_launch(void* const* d_in, const int* in_sizes, int n_in,
                              void* d_out, int out_size, void* d_ws, size_t ws_size,
                              hipStream_t stream){
  const float* of   = (const float*)d_in[0];
  const float* mf   = (const float*)d_in[1];
  const float* mask = (const float*)d_in[2];
  const float* qw   = (const float*)d_in[3];
  const float* qb   = (const float*)d_in[4];
  const float* kvw  = (const float*)d_in[5];
  const float* kvb  = (const float*)d_in[6];
  const float* scw  = (const float*)d_in[7];
  const float* scb  = (const float*)d_in[8];
  const float* outw = (const float*)d_in[9];
  const float* outb = (const float*)d_in[10];
  float* out = (float*)d_out;

  char* ws = (char*)d_ws;
  unsigned short* ofTk = (unsigned short*)(ws);             // 8 MiB
  unsigned short* w2t  = (unsigned short*)(ws + 8388608);   // 32 KiB
  float* c2   = (float*)(ws + 8421376);
  float* sqp  = (float*)(ws + 8421888);
  float* skp  = (float*)(ws + 8454656);
  float* qv   = (float*)(ws + 8585728);
  float* kvv  = (float*)(ws + 8586240);
  float* cqck = (float*)(ws + 8586752);
  const size_t fixed_end = 8587008;

  // units = 512 << csl2 (one wave each); prefer 8-way C-split
  int csl2 = 3;
  while (csl2 > 2){
    size_t nunit = (size_t)512 << csl2;
    if (fixed_end + nunit*16*4 + nunit*2048*4 <= ws_size) break;
    --csl2;
  }
  size_t nunit = (size_t)512 << csl2;
  float* prs  = (float*)(ws + fixed_end);
  float* pacc = (float*)(ws + fixed_end + nunit*16*4);
  int nblk = (int)(nunit >> 2);

  prep_vecs<<<1, 128, 0, stream>>>(qw, qb, kvw, kvb, scw, scb, qv, kvv, cqck);
  prep_w2<<<65, 256, 0, stream>>>(kvw, kvb, outw, outb, w2t, c2);
  prep_sq<<<2048, 256, 0, stream>>>(mf, qv, cqck, sqp);
  prep_sk_tr<<<512, 256, 0, stream>>>(of, kvv, cqck, skp, ofTk);
  if (csl2 == 3)
    attn_main<3><<<nblk, 256, 0, stream>>>(mask, sqp, skp, ofTk, pacc, prs);
  else
    attn_main<2><<<nblk, 256, 0, stream>>>(mask, sqp, skp, ofTk, pacc, prs);
  reduce_gemm2<<<128, 256, 0, stream>>>(pacc, prs, w2t, c2, out, csl2);
}

// Round 13
// 79.733 us; speedup vs baseline: 1.3819x; 1.3819x over previous
//
#include <hip/hip_runtime.h>
#include <hip/hip_bf16.h>

typedef __attribute__((ext_vector_type(8))) short short8;
typedef __attribute__((ext_vector_type(8))) unsigned short u16x8;
typedef __attribute__((ext_vector_type(4))) unsigned short u16x4;
typedef __attribute__((ext_vector_type(4))) float f32x4;
typedef __attribute__((ext_vector_type(4))) unsigned int u32x4;

#define L2E 1.44269504f

__device__ __forceinline__ unsigned short f2bf(float f){
  unsigned u = __float_as_uint(f);
  u += 0x7fffu + ((u >> 16) & 1u);
  return (unsigned short)(u >> 16);
}
// pack two f32 -> u32 of 2 bf16, RNE, lo in bits[15:0]
__device__ __forceinline__ unsigned pk_bf16(float lo, float hi){
  unsigned a = __float_as_uint(lo);
  a += 0x7fffu + ((a >> 16) & 1u);
  unsigned b = __float_as_uint(hi);
  b += 0x7fffu + ((b >> 16) & 1u);
  return (a >> 16) | (b & 0xffff0000u);
}
// async global->LDS, 16B per lane: LDS dest = uniform base + lane*16,
// global src = per-lane address. Counts on vmcnt.
__device__ __forceinline__ void gl_lds16(const void* g, void* l){
  __builtin_amdgcn_global_load_lds(
      (const __attribute__((address_space(1))) unsigned*)g,
      (__attribute__((address_space(3))) unsigned*)l, 16, 0, 0);
}

// ---------------- prep: fold score_w through q_w / kv_w ----------------
__global__ void prep_vecs(const float* __restrict__ qw, const float* __restrict__ qb,
                          const float* __restrict__ kvw, const float* __restrict__ kvb,
                          const float* __restrict__ scw, const float* __restrict__ scb,
                          float* __restrict__ qv, float* __restrict__ kvv,
                          float* __restrict__ cqck){
  int d = threadIdx.x; // 0..127
  const float4* qr = (const float4*)(qw + d*128);
  const float4* kr = (const float4*)(kvw + d*256);
  float a = 0.f, c = 0.f;
  #pragma unroll 8
  for (int i = 0; i < 32; ++i){
    float4 q4 = qr[i];
    float4 w4 = *(const float4*)(scw + i*4);
    a = fmaf(q4.x, w4.x, a); a = fmaf(q4.y, w4.y, a);
    a = fmaf(q4.z, w4.z, a); a = fmaf(q4.w, w4.w, a);
    float4 k4 = kr[i];
    float4 v4 = *(const float4*)(scw + 128 + i*4);
    c = fmaf(k4.x, v4.x, c); c = fmaf(k4.y, v4.y, c);
    c = fmaf(k4.z, v4.z, c); c = fmaf(k4.w, v4.w, c);
  }
  qv[d] = a; kvv[d] = c;
  if (d == 0){
    float cq = scb[0], ck = 0.f;
    #pragma unroll 8
    for (int i = 0; i < 32; ++i){
      float4 qb4 = *(const float4*)(qb + i*4);
      float4 w4  = *(const float4*)(scw + i*4);
      float4 kb4 = *(const float4*)(kvb + i*4);
      float4 v4  = *(const float4*)(scw + 128 + i*4);
      cq = fmaf(qb4.x, w4.x, cq); cq = fmaf(qb4.y, w4.y, cq);
      cq = fmaf(qb4.z, w4.z, cq); cq = fmaf(qb4.w, w4.w, cq);
      ck = fmaf(kb4.x, v4.x, ck); ck = fmaf(kb4.y, v4.y, ck);
      ck = fmaf(kb4.w, v4.w, ck); ck = fmaf(kb4.z, v4.z, ck);
    }
    cqck[0] = cq; cqck[1] = ck;
  }
}

// W2T[ho][din] = sum_h kv_w[din][128+h] * out_w[h][ho]   (bf16, transposed)
__global__ __launch_bounds__(256) void prep_w2(const float* __restrict__ kvw,
                          const float* __restrict__ kvb,
                          const float* __restrict__ outw, const float* __restrict__ outb,
                          unsigned short* __restrict__ w2t, float* __restrict__ c2){
  int blk = blockIdx.x;
  if (blk < 64){
    int idx = blk*256 + threadIdx.x;
    int di = idx >> 7, ho = idx & 127;
    const float* kr = kvw + di*256 + 128;
    float s = 0.f;
    for (int h = 0; h < 128; ++h) s = fmaf(kr[h], outw[h*128 + ho], s);
    w2t[ho*128 + di] = f2bf(s);
  } else if (threadIdx.x < 128){
    int ho = threadIdx.x;
    float s = outb[ho];
    for (int h = 0; h < 128; ++h) s = fmaf(kvb[128 + h], outw[h*128 + ho], s);
    c2[ho] = s;
  }
}

// sq'[b*1024+m] = L2E * (mf[b,m,:].qv + cq)
__global__ __launch_bounds__(256) void prep_sq(const float* __restrict__ mf,
                          const float* __restrict__ qv, const float* __restrict__ cqck,
                          float* __restrict__ sqp){
  int row = blockIdx.x*4 + (threadIdx.x >> 6);
  int lane = threadIdx.x & 63;
  float s = mf[row*128 + lane] * qv[lane] + mf[row*128 + 64 + lane] * qv[64 + lane];
  #pragma unroll
  for (int o = 32; o; o >>= 1) s += __shfl_xor(s, o, 64);
  if (lane == 0) sqp[row] = L2E * (s + cqck[0]);
}

// sk'[b*4096+c] = L2E*(of[b,c,:].kvv + ck)
// ofTk[b][ksg(128)][l4(4)][d(128)][8] = bf16(of[b][c][d]), c = ksg*32+l4*8+j
__global__ __launch_bounds__(256) void prep_sk_tr(const float* __restrict__ of,
                          const float* __restrict__ kvv, const float* __restrict__ cqck,
                          float* __restrict__ skp, unsigned short* __restrict__ ofTk){
  __shared__ unsigned short tile[64*130];
  int b  = blockIdx.x >> 6;
  int c0 = (blockIdx.x & 63) << 6;
  int t  = threadIdx.x;
  int r  = t >> 2, dq = (t & 3) << 5;
  const float* src = of + ((size_t)(b*4096 + c0 + r))*128 + dq;
  float part = 0.f;
  #pragma unroll
  for (int j = 0; j < 32; j += 4){
    float4 v = *(const float4*)(src + j);
    part = fmaf(v.x, kvv[dq + j],     part);
    part = fmaf(v.y, kvv[dq + j + 1], part);
    part = fmaf(v.z, kvv[dq + j + 2], part);
    part = fmaf(v.w, kvv[dq + j + 3], part);
    tile[r*130 + dq + j]     = f2bf(v.x);
    tile[r*130 + dq + j + 1] = f2bf(v.y);
    tile[r*130 + dq + j + 2] = f2bf(v.z);
    tile[r*130 + dq + j + 3] = f2bf(v.w);
  }
  part += __shfl_xor(part, 1, 64);
  part += __shfl_xor(part, 2, 64);
  if ((t & 3) == 0) skp[b*4096 + c0 + r] = L2E * (part + cqck[1]);
  __syncthreads();
  int d = t >> 1, chh = (t & 1) << 5;
  #pragma unroll
  for (int j = 0; j < 4; ++j){
    int cg = c0 + chh + j*8;
    int ksg = cg >> 5, l4g = (cg >> 3) & 3;
    u16x8 v;
    #pragma unroll
    for (int k = 0; k < 8; ++k) v[k] = tile[(chh + j*8 + k)*130 + d];
    *(u16x8*)(ofTk + (((size_t)(b*128 + ksg)*4 + l4g)*128 + d)*8) = v;
  }
}

// ---------------- main kernel: LDS mask ring + counted vmcnt ----------------
// Wave-private unit = (bmt=b*64+mt16, cs): 16 m-rows x 128 d, c-slice of
// 4096>>CSL2 in K-steps of 32 c. Mask streamed HBM->LDS ring (depth 4) via
// global_load_lds (zero VGPR in flight); sk slice preloaded to LDS once.
// B (ofTk, L2/L3-resident) JIT register loads. Counted vmcnt per kstep is the
// formal M-readiness guard; ring slot reuse guarded by lgkmcnt(0) before the
// overwriting DMA issue. Rowsum via ones-MFMA.
// R13: __launch_bounds__(256,2) — R12's (256,4) made the backend target 8
// waves/EU (64 VGPR) and spill ~109 MB of scratch per dispatch.

#define WVAL(KS) ((KS)==0 ? 0 : (KS)==1 ? 10 : (KS)==2 ? 20 : \
                  ((KS) >= NK-3 ? (24 + 2*(NK-1-(KS))) : 30))

#define KSTEP(KS) if ((KS) < NK) {                                               \
  asm volatile("s_waitcnt vmcnt(%0)" :: "i"(WVAL(KS)) : "memory");               \
  __builtin_amdgcn_sched_barrier(0);                                             \
  const unsigned short* bp = bbase + (size_t)(KS)*4096;                          \
  short8 b0 = *(const short8*)(bp);       short8 b1 = *(const short8*)(bp+128);  \
  short8 b2 = *(const short8*)(bp+256);   short8 b3 = *(const short8*)(bp+384);  \
  short8 b4 = *(const short8*)(bp+512);   short8 b5 = *(const short8*)(bp+640);  \
  short8 b6 = *(const short8*)(bp+768);   short8 b7 = *(const short8*)(bp+896);  \
  const char* ms = Mring + ((KS)&3)*2048;                                        \
  f32x4 m0v = *(const f32x4*)(ms + lB);                                          \
  f32x4 m1v = *(const f32x4*)(ms + 1024 + lB);                                   \
  f32x4 s0v = *(const f32x4*)(Sl + (KS)*128 + l4*32);                            \
  f32x4 s1v = *(const f32x4*)(Sl + (KS)*128 + l4*32 + 16);                       \
  asm volatile("s_waitcnt lgkmcnt(0)" ::: "memory");                             \
  __builtin_amdgcn_sched_barrier(0);                                             \
  if ((KS)+4 < NK){                                                              \
    gl_lds16(mrow + ((KS)+4)*32,     Mring + (((KS)+4)&3)*2048);                 \
    gl_lds16(mrow + ((KS)+4)*32 + 4, Mring + (((KS)+4)&3)*2048 + 1024);          \
  }                                                                              \
  float sx[8] = {s0v[0],s0v[1],s0v[2],s0v[3],s1v[0],s1v[1],s1v[2],s1v[3]};       \
  float mx[8] = {m0v[0],m0v[1],m0v[2],m0v[3],m1v[0],m1v[1],m1v[2],m1v[3]};       \
  float pv[8];                                                                   \
  _Pragma("unroll")                                                              \
  for (int j = 0; j < 8; ++j){                                                   \
    float s = sqv + sx[j];            /* log2-domain (pre-scaled by L2E) */      \
    s = fmaxf(s, 0.01f*s);            /* leaky (positively homogeneous) */       \
    s *= mx[j];                       /* mask: 0 -> exp2(0)=1 */                 \
    pv[j] = __builtin_amdgcn_exp2f(s);                                           \
  }                                                                              \
  u32x4 pkv;                                                                     \
  pkv[0] = pk_bf16(pv[0], pv[1]);  pkv[1] = pk_bf16(pv[2], pv[3]);               \
  pkv[2] = pk_bf16(pv[4], pv[5]);  pkv[3] = pk_bf16(pv[6], pv[7]);               \
  short8 pa = __builtin_bit_cast(short8, pkv);                                   \
  accS = __builtin_amdgcn_mfma_f32_16x16x32_bf16(pa, ones, accS, 0, 0, 0);       \
  acc0 = __builtin_amdgcn_mfma_f32_16x16x32_bf16(pa, b0, acc0, 0, 0, 0);         \
  acc1 = __builtin_amdgcn_mfma_f32_16x16x32_bf16(pa, b1, acc1, 0, 0, 0);         \
  acc2 = __builtin_amdgcn_mfma_f32_16x16x32_bf16(pa, b2, acc2, 0, 0, 0);         \
  acc3 = __builtin_amdgcn_mfma_f32_16x16x32_bf16(pa, b3, acc3, 0, 0, 0);         \
  acc4 = __builtin_amdgcn_mfma_f32_16x16x32_bf16(pa, b4, acc4, 0, 0, 0);         \
  acc5 = __builtin_amdgcn_mfma_f32_16x16x32_bf16(pa, b5, acc5, 0, 0, 0);         \
  acc6 = __builtin_amdgcn_mfma_f32_16x16x32_bf16(pa, b6, acc6, 0, 0, 0);         \
  acc7 = __builtin_amdgcn_mfma_f32_16x16x32_bf16(pa, b7, acc7, 0, 0, 0);         \
}

template<int CSL2>
__global__ __launch_bounds__(256, 2) void attn_main(
    const float* __restrict__ mask, const float* __restrict__ sqp,
    const float* __restrict__ skp, const unsigned short* __restrict__ ofTk,
    float* __restrict__ pacc, float* __restrict__ prs)
{
  constexpr int CS = 1 << CSL2;
  constexpr int NK = 128 >> CSL2;               // K-steps of 32 c
  constexpr int SBYTES = (4096 >> CSL2) * 4;    // sk slice bytes
  constexpr int SINSTS = SBYTES / 1024;
  __shared__ char lds[4][4*2048 + SBYTES];      // per-wave: 8KB M ring + S

  const int t = threadIdx.x, w = t >> 6, l = t & 63;
  const int l15 = l & 15, l4 = l >> 4;
  const int lB = l * 16;
  const int unit = blockIdx.x*4 + w;
  const int cs   = unit & (CS - 1);
  const int bmt  = unit >> CSL2;                // b*64 + mt16
  const int b    = bmt >> 6;
  const int m0   = (bmt & 63) << 4;
  const int c0   = cs << (12 - CSL2);

  char* Mring = &lds[w][0];
  char* Sl    = &lds[w][8192];

  const int grow = b*1024 + m0 + l15;
  const float sqv = sqp[grow];
  const float* mrow = mask + (size_t)grow*4096 + c0 + l4*8;   // per-lane src
  const float* srow = skp + b*4096 + c0;
  const unsigned short* bbase =
      ofTk + (((size_t)(b*128 + (c0 >> 5))*4 + l4)*128 + l15)*8;

  const short one_bf = (short)0x3F80;
  const short8 ones = {one_bf,one_bf,one_bf,one_bf,one_bf,one_bf,one_bf,one_bf};

  f32x4 acc0={0,0,0,0},acc1={0,0,0,0},acc2={0,0,0,0},acc3={0,0,0,0},
        acc4={0,0,0,0},acc5={0,0,0,0},acc6={0,0,0,0},acc7={0,0,0,0},
        accS={0,0,0,0};

  // prologue: S slice, then M ring slots 0..3
  #pragma unroll
  for (int i = 0; i < SINSTS; ++i)
    gl_lds16(srow + l*4 + i*256, Sl + i*1024);
  #pragma unroll
  for (int p = 0; p < 4; ++p){
    gl_lds16(mrow + p*32,     Mring + p*2048);
    gl_lds16(mrow + p*32 + 4, Mring + p*2048 + 1024);
  }

  KSTEP(0)  KSTEP(1)  KSTEP(2)  KSTEP(3)  KSTEP(4)  KSTEP(5)  KSTEP(6)  KSTEP(7)
  KSTEP(8)  KSTEP(9)  KSTEP(10) KSTEP(11) KSTEP(12) KSTEP(13) KSTEP(14) KSTEP(15)
  KSTEP(16) KSTEP(17) KSTEP(18) KSTEP(19) KSTEP(20) KSTEP(21) KSTEP(22) KSTEP(23)
  KSTEP(24) KSTEP(25) KSTEP(26) KSTEP(27) KSTEP(28) KSTEP(29) KSTEP(30) KSTEP(31)

  // rowsum from ones-MFMA: lane (l15==0, l4) holds rows l4*4+j
  if (l15 == 0) *(f32x4*)(prs + unit*16 + l4*4) = accS;

  // acc -> pacc[unit][col][row] (col = nt*16+l15, rows l4*4..+3)
  float* po = pacc + (size_t)unit*2048 + l15*16 + l4*4;
  *(f32x4*)(po + 0*256) = acc0;  *(f32x4*)(po + 1*256) = acc1;
  *(f32x4*)(po + 2*256) = acc2;  *(f32x4*)(po + 3*256) = acc3;
  *(f32x4*)(po + 4*256) = acc4;  *(f32x4*)(po + 5*256) = acc5;
  *(f32x4*)(po + 6*256) = acc6;  *(f32x4*)(po + 7*256) = acc7;
}

// ---------------- reduce partials + normalize + GEMM2 ----------------
__global__ __launch_bounds__(256) void reduce_gemm2(
    const float* __restrict__ pacc, const float* __restrict__ prs,
    const unsigned short* __restrict__ w2t, const float* __restrict__ c2,
    float* __restrict__ out, int csl2)
{
  __shared__ unsigned short A2[64*128];   // 16 KB, row stride 256 B, swizzled
  __shared__ float rs[64];                // inverse rowsums
  const int bmt64 = blockIdx.x;
  const int b = bmt64 >> 4, mt = bmt64 & 15;
  const int CS = 1 << csl2;
  const int t = threadIdx.x;

  f32x4 a[8];
  #pragma unroll
  for (int i = 0; i < 8; ++i) a[i] = {0.f,0.f,0.f,0.f};
  for (int cs = 0; cs < CS; ++cs){
    #pragma unroll
    for (int i = 0; i < 8; ++i){
      const int flat = (i*256 + t)*4;
      const int q = flat >> 11, f2 = flat & 2047;
      const float* pb = pacc + ((size_t)((bmt64*4 + q)*CS + cs))*2048 + f2;
      f32x4 v = *(const f32x4*)pb;
      a[i][0]+=v[0]; a[i][1]+=v[1]; a[i][2]+=v[2]; a[i][3]+=v[3];
    }
  }
  if (t < 64){
    float s = 0.f;
    const int q = t >> 4, r16 = t & 15;
    for (int cs = 0; cs < CS; ++cs) s += prs[((bmt64*4 + q)*CS + cs)*16 + r16];
    rs[t] = 1.f / s;
  }
  __syncthreads();
  #pragma unroll
  for (int i = 0; i < 8; ++i){
    const int flat = (i*256 + t)*4;
    const int q = flat >> 11, f2 = flat & 2047;
    const int col = f2 >> 4, r16 = f2 & 15;
    #pragma unroll
    for (int k = 0; k < 4; ++k){
      const int row = q*16 + r16 + k;
      unsigned short h = f2bf(a[i][k] * rs[row]);
      *(unsigned short*)((char*)A2 + row*256 + ((col*2) ^ ((row & 7) << 4))) = h;
    }
  }
  __syncthreads();

  const int w = t >> 6, l = t & 63, l15 = l & 15, l4 = l >> 4;
  f32x4 o[4][2];
  #pragma unroll
  for (int mf = 0; mf < 4; ++mf){ o[mf][0] = {0.f,0.f,0.f,0.f}; o[mf][1] = {0.f,0.f,0.f,0.f}; }
  const unsigned short* wp0 = w2t + (size_t)(w*32 + l15)*128 + l4*8;
  const char* ab = (const char*)A2 + l15*256;
  const int xa = (l15 & 7) << 4;
  #pragma unroll
  for (int ks = 0; ks < 4; ++ks){
    short8 b0 = *(const short8*)(wp0 + ks*32);
    short8 b1 = *(const short8*)(wp0 + 16*128 + ks*32);
    #pragma unroll
    for (int mf = 0; mf < 4; ++mf){
      short8 af = *(const short8*)(ab + mf*4096 + ((ks*64 + l4*16) ^ xa));
      o[mf][0] = __builtin_amdgcn_mfma_f32_16x16x32_bf16(af, b0, o[mf][0], 0, 0, 0);
      o[mf][1] = __builtin_amdgcn_mfma_f32_16x16x32_bf16(af, b1, o[mf][1], 0, 0, 0);
    }
  }
  #pragma unroll
  for (int mf = 0; mf < 4; ++mf)
    #pragma unroll
    for (int n = 0; n < 2; ++n){
      const int col = w*32 + n*16 + l15;
      const float cc = c2[col];
      #pragma unroll
      for (int j = 0; j < 4; ++j){
        const int row = mf*16 + l4*4 + j;
        out[((size_t)(b*1024 + mt*64 + row))*128 + col] = o[mf][n][j] + cc;
      }
    }
}

extern "C" void kernel_launch(void* const* d_in, const int* in_sizes, int n_in,
                              void* d_out, int out_size, void* d_ws, size_t ws_size,
                              hipStream_t stream){
  const float* of   = (const float*)d_in[0];
  const float* mf   = (const float*)d_in[1];
  const float* mask = (const float*)d_in[2];
  const float* qw   = (const float*)d_in[3];
  const float* qb   = (const float*)d_in[4];
  const float* kvw  = (const float*)d_in[5];
  const float* kvb  = (const float*)d_in[6];
  const float* scw  = (const float*)d_in[7];
  const float* scb  = (const float*)d_in[8];
  const float* outw = (const float*)d_in[9];
  const float* outb = (const float*)d_in[10];
  float* out = (float*)d_out;

  char* ws = (char*)d_ws;
  unsigned short* ofTk = (unsigned short*)(ws);             // 8 MiB
  unsigned short* w2t  = (unsigned short*)(ws + 8388608);   // 32 KiB
  float* c2   = (float*)(ws + 8421376);
  float* sqp  = (float*)(ws + 8421888);
  float* skp  = (float*)(ws + 8454656);
  float* qv   = (float*)(ws + 8585728);
  float* kvv  = (float*)(ws + 8586240);
  float* cqck = (float*)(ws + 8586752);
  const size_t fixed_end = 8587008;

  // units = 512 << csl2 (one wave each); prefer 8-way C-split
  int csl2 = 3;
  while (csl2 > 2){
    size_t nunit = (size_t)512 << csl2;
    if (fixed_end + nunit*16*4 + nunit*2048*4 <= ws_size) break;
    --csl2;
  }
  size_t nunit = (size_t)512 << csl2;
  float* prs  = (float*)(ws + fixed_end);
  float* pacc = (float*)(ws + fixed_end + nunit*16*4);
  int nblk = (int)(nunit >> 2);

  prep_vecs<<<1, 128, 0, stream>>>(qw, qb, kvw, kvb, scw, scb, qv, kvv, cqck);
  prep_w2<<<65, 256, 0, stream>>>(kvw, kvb, outw, outb, w2t, c2);
  prep_sq<<<2048, 256, 0, stream>>>(mf, qv, cqck, sqp);
  prep_sk_tr<<<512, 256, 0, stream>>>(of, kvv, cqck, skp, ofTk);
  if (csl2 == 3)
    attn_main<3><<<nblk, 256, 0, stream>>>(mask, sqp, skp, ofTk, pacc, prs);
  else
    attn_main<2><<<nblk, 256, 0, stream>>>(mask, sqp, skp, ofTk, pacc, prs);
  reduce_gemm2<<<128, 256, 0, stream>>>(pacc, prs, w2t, c2, out, csl2);
}